// Round 9
// baseline (512.272 us; speedup 1.0000x reference)
//
#include <hip/hip_runtime.h>
#include <hip/hip_bf16.h>

#define NN 100000
#define NE 1280000
#define DD 64
#define NRANGE 98            // ceil(NN/1024)
#define NGROUPS (NN / 16)    // 6250
#define GG 1536              // persistent gemm grid (6 blocks/CU)

typedef __attribute__((ext_vector_type(8))) short bf16x8;
typedef __attribute__((ext_vector_type(4))) float f32x4;

static __device__ __forceinline__ unsigned short f2bf(float f) {
    __hip_bfloat16 h = __float2bfloat16(f);
    return *reinterpret_cast<unsigned short*>(&h);
}

// ---------------------------------------------------------------------------
// Combined: x(fp32)->bf16 convert + dst histograms (per-node deg via global
// atomics [L2-resident 400 KB] + per-range counts via LDS staging).
// Grid 6250: x slice = 1024 floats/block (exact), edge slice = 205/block.
// ---------------------------------------------------------------------------
__global__ __launch_bounds__(256) void hist_conv_kernel(
    const float* __restrict__ x, const int* __restrict__ dst,
    unsigned short* __restrict__ xb, int* __restrict__ deg,
    int* __restrict__ rangeCnt)
{
    __shared__ int h[128];
    int tid = threadIdx.x, bid = blockIdx.x;
    if (tid < 128) h[tid] = 0;
    __syncthreads();

    // convert 4 floats
    int i = (bid * 256 + tid) * 4;
    float4 v = *(const float4*)(x + i);
    ushort4 o;
    o.x = f2bf(v.x); o.y = f2bf(v.y); o.z = f2bf(v.z); o.w = f2bf(v.w);
    *(ushort4*)(xb + i) = o;

    // histogram 205 edges per block
    if (tid < 205) {
        int e = bid * 205 + tid;
        if (e < NE) {
            int d = dst[e];
            atomicAdd(&deg[d], 1);
            atomicAdd(&h[d >> 10], 1);
        }
    }
    __syncthreads();
    if (tid < NRANGE && h[tid]) atomicAdd(&rangeCnt[tid], h[tid]);
}

// ---------------------------------------------------------------------------
// Exclusive scan of 98 range counts -> rangeBase[99] + gcur (P1 cursors).
// ---------------------------------------------------------------------------
__global__ __launch_bounds__(128) void scan98_kernel(
    const int* __restrict__ rangeCnt, int* __restrict__ rangeBase,
    int* __restrict__ gcur, int* __restrict__ rowptr)
{
    __shared__ int sd[128];
    int tid = threadIdx.x;
    int v = (tid < NRANGE) ? rangeCnt[tid] : 0;
    sd[tid] = v;
    __syncthreads();
    for (int o = 1; o < 128; o <<= 1) {
        int t = (tid >= o) ? sd[tid - o] : 0;
        __syncthreads();
        sd[tid] += t;
        __syncthreads();
    }
    if (tid < NRANGE) { int ex = sd[tid] - v; rangeBase[tid] = ex; gcur[tid] = ex; }
    if (tid == 0) { rangeBase[NRANGE] = NE; rowptr[NN] = NE; }
}

// ---------------------------------------------------------------------------
// P1: coarse bin by dst range, block-synchronous LDS staging (grouped runs
// of ~10 records -> ~84 B writes instead of random 8 B). Grid 1250 (exact).
// rec.x = src | (dst&1023)<<17 ; rec.y = w bits.
// ---------------------------------------------------------------------------
__global__ __launch_bounds__(256) void p1_bin_kernel(
    const int* __restrict__ src, const int* __restrict__ dst,
    const float* __restrict__ w, int* __restrict__ gcur,
    int2* __restrict__ ecoarse)
{
    __shared__ int2 stage[1024];
    __shared__ unsigned char sbkt[1024];
    __shared__ int cnt[128], ofs[128], gpos[128], sd[128];

    int tid = threadIdx.x;
    int e0 = blockIdx.x * 1024 + tid * 4;
    int4   s4 = *(const int4*)(src + e0);
    int4   d4 = *(const int4*)(dst + e0);
    float4 w4 = *(const float4*)(w + e0);

    if (tid < 128) cnt[tid] = 0;
    __syncthreads();

    int ss[4] = {s4.x, s4.y, s4.z, s4.w};
    int dd[4] = {d4.x, d4.y, d4.z, d4.w};
    float ww[4] = {w4.x, w4.y, w4.z, w4.w};
    int b[4], p[4];
#pragma unroll
    for (int i = 0; i < 4; ++i) {
        b[i] = dd[i] >> 10;
        p[i] = atomicAdd(&cnt[b[i]], 1);
    }
    __syncthreads();

    int cv = (tid < 128) ? cnt[tid] : 0;
    if (tid < 128) sd[tid] = cv;
    __syncthreads();
    for (int o = 1; o < 128; o <<= 1) {
        int t = (tid >= o && tid < 128) ? sd[tid - o] : 0;
        __syncthreads();
        if (tid < 128) sd[tid] += t;
        __syncthreads();
    }
    if (tid < 128) ofs[tid] = sd[tid] - cv;
    if (tid < NRANGE && cv > 0) gpos[tid] = atomicAdd(&gcur[tid], cv);
    __syncthreads();

#pragma unroll
    for (int i = 0; i < 4; ++i) {
        int slot = ofs[b[i]] + p[i];
        stage[slot] = make_int2(ss[i] | ((dd[i] & 1023) << 17), __float_as_int(ww[i]));
        sbkt[slot] = (unsigned char)b[i];
    }
    __syncthreads();

    for (int j = tid; j < 1024; j += 256) {
        int bb = sbkt[j];
        ecoarse[gpos[bb] + (j - ofs[bb])] = stage[j];
    }
}

// ---------------------------------------------------------------------------
// Per-range node scan: block r scans deg over nodes [r*1024, r*1024+1024),
// seeded by rangeBase[r] -> rowptr + cursor. Pure LDS scan, no pass over
// edges. Grid NRANGE.
// ---------------------------------------------------------------------------
__global__ __launch_bounds__(256) void scan_nodes_kernel(
    const int* __restrict__ deg, const int* __restrict__ rangeBase,
    int* __restrict__ rowptr, int* __restrict__ cursor)
{
    __shared__ int ssum[256];
    int r = blockIdx.x, tid = threadIdx.x;
    int n0 = r * 1024 + tid * 4;
    int v[4];
    int s = 0;
#pragma unroll
    for (int t = 0; t < 4; ++t) { v[t] = (n0 + t < NN) ? deg[n0 + t] : 0; s += v[t]; }
    ssum[tid] = s;
    __syncthreads();
    for (int o = 1; o < 256; o <<= 1) {
        int t = (tid >= o) ? ssum[tid - o] : 0;
        __syncthreads();
        ssum[tid] += t;
        __syncthreads();
    }
    int run = rangeBase[r] + ssum[tid] - s;
#pragma unroll
    for (int t = 0; t < 4; ++t) {
        if (n0 + t < NN) { rowptr[n0 + t] = run; cursor[n0 + t] = run; }
        run += v[t];
    }
}

// ---------------------------------------------------------------------------
// Place: 16 sub-blocks per range (grid 1568), each a contiguous chunk of the
// range's ecoarse slice. Cursor atomics are L2-hot (4 KB window); ebuf writes
// land in the range's L2-resident ~105 KB window -> full-line writebacks.
// ---------------------------------------------------------------------------
__global__ __launch_bounds__(256) void place_kernel(
    const int2* __restrict__ ecoarse, const int* __restrict__ rangeBase,
    int* __restrict__ cursor, int2* __restrict__ ebuf)
{
    int r = blockIdx.x >> 4;
    int sub = blockIdx.x & 15;
    int beg = rangeBase[r], end = rangeBase[r + 1];
    int len = end - beg;
    int chunk = (len + 15) >> 4;
    int j0 = beg + sub * chunk;
    int j1 = min(j0 + chunk, end);
    int rbase = r << 10;
    for (int j = j0 + threadIdx.x; j < j1; j += 256) {
        int2 rec = ecoarse[j];
        int node = rbase + ((rec.x >> 17) & 1023);
        int p = atomicAdd(&cursor[node], 1);
        ebuf[p] = make_int2(rec.x & 0x1FFFF, rec.y);
    }
}

// ---------------------------------------------------------------------------
// CSR gather over bf16 rows -> bf16 agg (R6 structure: wave per node,
// lane=feature, unroll-4 MLP, no LDS). Grid 25000 (exact).
// ---------------------------------------------------------------------------
__global__ __launch_bounds__(256) void csr_agg_bf16_kernel(
    const unsigned short* __restrict__ hb, const int* __restrict__ rowptr,
    const int2* __restrict__ ebuf, unsigned short* __restrict__ aggb)
{
    int lane = threadIdx.x & 63;
    int node = blockIdx.x * 4 + (threadIdx.x >> 6);
    int beg = __builtin_amdgcn_readfirstlane(rowptr[node]);
    int end = __builtin_amdgcn_readfirstlane(rowptr[node + 1]);

    float a0 = 0.f, a1 = 0.f, a2 = 0.f, a3 = 0.f;
    int j = beg;
    for (; j + 4 <= end; j += 4) {
        int2 e0 = ebuf[j], e1 = ebuf[j + 1], e2 = ebuf[j + 2], e3 = ebuf[j + 3];
        unsigned short u0 = hb[(size_t)e0.x * DD + lane];
        unsigned short u1 = hb[(size_t)e1.x * DD + lane];
        unsigned short u2 = hb[(size_t)e2.x * DD + lane];
        unsigned short u3 = hb[(size_t)e3.x * DD + lane];
        a0 = fmaf(__int_as_float(e0.y), __uint_as_float((unsigned)u0 << 16), a0);
        a1 = fmaf(__int_as_float(e1.y), __uint_as_float((unsigned)u1 << 16), a1);
        a2 = fmaf(__int_as_float(e2.y), __uint_as_float((unsigned)u2 << 16), a2);
        a3 = fmaf(__int_as_float(e3.y), __uint_as_float((unsigned)u3 << 16), a3);
    }
    for (; j < end; ++j) {
        int2 e0 = ebuf[j];
        unsigned short u0 = hb[(size_t)e0.x * DD + lane];
        a0 = fmaf(__int_as_float(e0.y), __uint_as_float((unsigned)u0 << 16), a0);
    }
    aggb[(size_t)node * DD + lane] = f2bf((a0 + a1) + (a2 + a3));
}

// ---------------------------------------------------------------------------
// MFMA dual GEMM (persistent, R6 structure): out[g*16..][n] =
// [aggb|hb] @ [Wrel;Wroot] + bias (+ReLU). B-frags in 16 VGPRs (loaded
// once/block); A staged to LDS in fragment order (double-buffered,
// 1 barrier/group); 4 MFMA/wave/group.
// ---------------------------------------------------------------------------
template <bool RELU, bool OUT32>
__global__ __launch_bounds__(256) void mfma_gemm_kernel(
    const unsigned short* __restrict__ aggb,
    const unsigned short* __restrict__ hb,
    const float* __restrict__ Wrel,
    const float* __restrict__ brel,
    const float* __restrict__ Wroot,
    void* __restrict__ outp)
{
    __shared__ __align__(16) unsigned short Ast[2][256][8];   // 8 KB

    int tid = threadIdx.x;
    int lane = tid & 63;
    int wv = tid >> 6;
    int quad = lane >> 4;
    int m16 = lane & 15;
    int n = wv * 16 + m16;

    bf16x8 bfrag[4];
#pragma unroll
    for (int t = 0; t < 4; ++t) {
#pragma unroll
        for (int j = 0; j < 8; ++j) {
            int k = t * 32 + quad * 8 + j;
            float wval = (k < 64) ? Wrel[k * 64 + n] : Wroot[(k - 64) * 64 + n];
            bfrag[t][j] = (short)f2bf(wval);
        }
    }
    float bias = brel[n];

    int ts = tid >> 6;
    int ls = tid & 63;
    int ms = ls & 15;
    int c0 = ts * 32 + (ls >> 4) * 8;
    bool fromAgg = (c0 < 64);
    int cOff = fromAgg ? c0 : (c0 - 64);

    int g = blockIdx.x;
    int buf = 0;
    while (g < NGROUPS) {
        {
            size_t row = (size_t)g * 16 + ms;
            const unsigned short* sp = (fromAgg ? aggb : hb) + row * DD + cOff;
            *(uint4*)&Ast[buf][tid][0] = *(const uint4*)sp;
        }
        __syncthreads();

        f32x4 c = {0.f, 0.f, 0.f, 0.f};
#pragma unroll
        for (int t = 0; t < 4; ++t) {
            bf16x8 a = *(const bf16x8*)&Ast[buf][t * 64 + lane][0];
            c = __builtin_amdgcn_mfma_f32_16x16x32_bf16(a, bfrag[t], c, 0, 0, 0);
        }

#pragma unroll
        for (int reg = 0; reg < 4; ++reg) {
            int row = quad * 4 + reg;
            size_t node = (size_t)g * 16 + row;
            float v = c[reg] + bias;
            if (RELU) v = fmaxf(v, 0.f);
            if (OUT32) ((float*)outp)[node * DD + n] = v;
            else       ((unsigned short*)outp)[node * DD + n] = f2bf(v);
        }
        g += GG;
        buf ^= 1;
    }
}

extern "C" void kernel_launch(void* const* d_in, const int* in_sizes, int n_in,
                              void* d_out, int out_size, void* d_ws, size_t ws_size,
                              hipStream_t stream)
{
    const float* x     = (const float*)d_in[0];
    const int*   ei    = (const int*)d_in[1];
    const float* w     = (const float*)d_in[2];
    const float* Wrel1 = (const float*)d_in[4];
    const float* brel1 = (const float*)d_in[5];
    const float* Wroot1= (const float*)d_in[6];
    const float* Wrel2 = (const float*)d_in[7];
    const float* brel2 = (const float*)d_in[8];
    const float* Wroot2= (const float*)d_in[9];
    const float* Wrel3 = (const float*)d_in[10];
    const float* brel3 = (const float*)d_in[11];
    const float* Wroot3= (const float*)d_in[12];

    float* out = (float*)d_out;

    // workspace (ws >= 256 MB): all regions distinct
    char* ws = (char*)d_ws;
    int2*  ebuf    = (int2*)ws;                       ws += (size_t)NE * 8;          // 10.24 MB
    int2*  ecoarse = (int2*)ws;                       ws += (size_t)NE * 8;          // 10.24 MB
    unsigned short* xb  = (unsigned short*)ws;        ws += (size_t)NN * DD * 2;     // 12.8 MB
    unsigned short* aggb= (unsigned short*)ws;        ws += (size_t)NN * DD * 2;     // 12.8 MB
    unsigned short* h1b = (unsigned short*)ws;        ws += (size_t)NN * DD * 2;     // 12.8 MB
    unsigned short* h2b = (unsigned short*)ws;        ws += (size_t)NN * DD * 2;     // 12.8 MB
    int*   deg     = (int*)ws;                        ws += (size_t)NN * 4;          // 0.4 MB
    int*   rangeCnt = (int*)ws;                       ws += (size_t)128 * 4;         // contiguous w/ deg
    int*   rangeBase = (int*)ws;                      ws += (size_t)129 * 4;
    int*   gcur    = (int*)ws;                        ws += (size_t)128 * 4;
    int*   rowptr  = (int*)ws;                        ws += (size_t)(NN + 1) * 4;
    int*   cursor  = (int*)ws;

    const int* src = ei;
    const int* dst = ei + NE;

    // ---- build ----
    hipMemsetAsync(deg, 0, ((size_t)NN + 128) * 4, stream);   // deg + rangeCnt
    hist_conv_kernel<<<6250, 256, 0, stream>>>(x, dst, xb, deg, rangeCnt);
    scan98_kernel<<<1, 128, 0, stream>>>(rangeCnt, rangeBase, gcur, rowptr);
    p1_bin_kernel<<<1250, 256, 0, stream>>>(src, dst, w, gcur, ecoarse);
    scan_nodes_kernel<<<NRANGE, 256, 0, stream>>>(deg, rangeBase, rowptr, cursor);
    place_kernel<<<NRANGE * 16, 256, 0, stream>>>(ecoarse, rangeBase, cursor, ebuf);

    // ---- Layer 1: gather(xb)->aggb ; gemm([aggb|xb])->h1b (bf16, ReLU) ----
    csr_agg_bf16_kernel<<<NN / 4, 256, 0, stream>>>(xb, rowptr, ebuf, aggb);
    mfma_gemm_kernel<true, false><<<GG, 256, 0, stream>>>(
        aggb, xb, Wrel1, brel1, Wroot1, h1b);

    // ---- Layer 2: gather(h1b)->aggb ; gemm([aggb|h1b])->h2b (bf16, ReLU) --
    csr_agg_bf16_kernel<<<NN / 4, 256, 0, stream>>>(h1b, rowptr, ebuf, aggb);
    mfma_gemm_kernel<true, false><<<GG, 256, 0, stream>>>(
        aggb, h1b, Wrel2, brel2, Wroot2, h2b);

    // ---- Layer 3: gather(h2b)->aggb ; gemm([aggb|h2b])->out (fp32) ----
    csr_agg_bf16_kernel<<<NN / 4, 256, 0, stream>>>(h2b, rowptr, ebuf, aggb);
    mfma_gemm_kernel<false, true><<<GG, 256, 0, stream>>>(
        aggb, h2b, Wrel3, brel3, Wroot3, out);
}